// Round 1
// baseline (258.348 us; speedup 1.0000x reference)
//
#include <hip/hip_runtime.h>
#include <hip/hip_bf16.h>

#define OUT_SCALE 0.030197383422318501f  // exp(-3.5)

typedef __attribute__((ext_vector_type(8))) short bf16x8;
typedef __attribute__((ext_vector_type(4))) float f32x4;

__device__ __forceinline__ unsigned short f2bf(float f) {
  unsigned u = __builtin_bit_cast(unsigned, f);
  u += 0x7fffu + ((u >> 16) & 1u);
  return (unsigned short)(u >> 16);
}

__device__ __forceinline__ float silu_f(float h) {
  return h / (1.0f + __expf(-h));
}

// ---------------------------------------------------------------------------
// EL kernel: 8 pairs/block, rows padded 31->32 per pair => 256 rows, 16 tiles.
// Adds OUT_SCALE*decay*ps_el into out (out pre-initialized by nuc kernel).
// ---------------------------------------------------------------------------
__global__ __launch_bounds__(256, 2) void bf_el_kernel(
    const float* __restrict__ rs, const float* __restrict__ msg,
    const float* __restrict__ emb, const float* __restrict__ w1,
    const float* __restrict__ b1, const float* __restrict__ w2,
    const float* __restrict__ b2, const float* __restrict__ coords,
    const float* __restrict__ chg, float* __restrict__ out) {
  __shared__ __align__(16) unsigned short s_emb[8 * 128];
  __shared__ __align__(16) unsigned short s_msg[256 * 128];
  __shared__ float s_fp[4][256];
  __shared__ float s_ps[8][4];
  __shared__ float s_decay[8];

  const int tid = threadIdx.x;
  const int bid = blockIdx.x;
  const int gp0 = bid * 8;  // first pair index (b*32+e)

  if (tid < 32) ((float*)s_ps)[tid] = 0.0f;

  // ---- stage emb (8 pairs x 128 f32 -> bf16) ----
  {
    int p = tid >> 5, c = tid & 31;
    float4 v = *(const float4*)(emb + (gp0 + p) * 128 + c * 4);
    ushort4 h;
    h.x = f2bf(v.x); h.y = f2bf(v.y); h.z = f2bf(v.z); h.w = f2bf(v.w);
    *(ushort4*)(s_emb + p * 128 + c * 4) = h;
  }

  // ---- stage msg (256 rows x 16 chunks of 8 bf16), XOR-swizzled chunks ----
#pragma unroll
  for (int it = 0; it < 16; ++it) {
    int id = it * 256 + tid;
    int r = id >> 4, c = id & 15;
    int p = r >> 5, j = r & 31;
    uint4 pk = {0u, 0u, 0u, 0u};
    if (j < 31) {
      const float* src = msg + ((gp0 + p) * 31 + j) * 128 + c * 8;
      float4 v0 = *(const float4*)src;
      float4 v1 = *(const float4*)(src + 4);
      pk.x = (unsigned)f2bf(v0.x) | ((unsigned)f2bf(v0.y) << 16);
      pk.y = (unsigned)f2bf(v0.z) | ((unsigned)f2bf(v0.w) << 16);
      pk.z = (unsigned)f2bf(v1.x) | ((unsigned)f2bf(v1.y) << 16);
      pk.w = (unsigned)f2bf(v1.z) | ((unsigned)f2bf(v1.w) << 16);
    }
    int sw = c ^ (r & 15);
    *(uint4*)(s_msg + r * 128 + sw * 8) = pk;
  }

  // ---- per-wave persistent W1 B-fragments (64 cols per wave) ----
  const int lane = tid & 63;
  const int wv = tid >> 6;
  const int cIdx = lane & 15, kg = lane >> 4;

  bf16x8 Bf[8][4];
  float b1v[4], w2v[4];
#pragma unroll
  for (int nt = 0; nt < 4; ++nt) {
    int col = wv * 64 + nt * 16 + cIdx;
    b1v[nt] = b1[col];
    w2v[nt] = w2[col];
#pragma unroll
    for (int kk = 0; kk < 8; ++kk) {
      int k0 = kk * 32 + kg * 8;
      const float* wp = w1 + k0 * 256 + col;
      bf16x8 f;
#pragma unroll
      for (int i = 0; i < 8; ++i) f[i] = (short)f2bf(wp[i * 256]);
      Bf[kk][nt] = f;
    }
  }

  __syncthreads();

  // ---- main loop: 16 M-tiles of 16 rows ----
#pragma unroll 1
  for (int t = 0; t < 16; ++t) {
    int p = t >> 1;
    int r = t * 16 + cIdx;
    int rx = r & 15;
    const unsigned short* ep = s_emb + p * 128 + kg * 8;
    const unsigned short* mp = s_msg + r * 128;
    f32x4 acc0 = {0, 0, 0, 0}, acc1 = {0, 0, 0, 0};
    f32x4 acc2 = {0, 0, 0, 0}, acc3 = {0, 0, 0, 0};
#pragma unroll
    for (int kk = 0; kk < 8; ++kk) {
      bf16x8 a;
      if (kk < 4) {
        a = *(const bf16x8*)(ep + kk * 32);
      } else {
        int sw = (((kk - 4) * 4 + kg) ^ rx);
        a = *(const bf16x8*)(mp + sw * 8);
      }
      acc0 = __builtin_amdgcn_mfma_f32_16x16x32_bf16(a, Bf[kk][0], acc0, 0, 0, 0);
      acc1 = __builtin_amdgcn_mfma_f32_16x16x32_bf16(a, Bf[kk][1], acc1, 0, 0, 0);
      acc2 = __builtin_amdgcn_mfma_f32_16x16x32_bf16(a, Bf[kk][2], acc2, 0, 0, 0);
      acc3 = __builtin_amdgcn_mfma_f32_16x16x32_bf16(a, Bf[kk][3], acc3, 0, 0, 0);
    }
    // fused layer-2: silu(h+b1)*w2, reduce over this wave's 64 cols
    float part[4] = {0, 0, 0, 0};
#define EPI(NT, ACC)                       \
  {                                        \
    float bb = b1v[NT], ww = w2v[NT];      \
    part[0] += silu_f(ACC[0] + bb) * ww;   \
    part[1] += silu_f(ACC[1] + bb) * ww;   \
    part[2] += silu_f(ACC[2] + bb) * ww;   \
    part[3] += silu_f(ACC[3] + bb) * ww;   \
  }
    EPI(0, acc0) EPI(1, acc1) EPI(2, acc2) EPI(3, acc3)
#undef EPI
#pragma unroll
    for (int rr = 0; rr < 4; ++rr) {
      float v = part[rr];
      v += __shfl_xor(v, 1);
      v += __shfl_xor(v, 2);
      v += __shfl_xor(v, 4);
      v += __shfl_xor(v, 8);
      if (cIdx == 0) s_fp[wv][t * 16 + kg * 4 + rr] = v;
    }
  }

  __syncthreads();

  // ---- geometry epilogue ----
  if (tid < 248) {
    int p = tid / 31, jj = tid - p * 31;
    int gp = gp0 + p, b = gp >> 5, i = gp & 31;
    int jidx = jj + (jj >= i ? 1 : 0);
    const float* rsb = rs + b * 96;
    float dx = rsb[jidx * 3 + 0] - rsb[i * 3 + 0];
    float dy = rsb[jidx * 3 + 1] - rsb[i * 3 + 1];
    float dz = rsb[jidx * 3 + 2] - rsb[i * 3 + 2];
    float tq = dx * dx + dy * dy + dz * dz;
    int row = p * 32 + jj;
    float f = s_fp[0][row] + s_fp[1][row] + s_fp[2][row] + s_fp[3][row] + b2[0];
    float g = f / (1.0f + tq * sqrtf(tq));
    atomicAdd(&s_ps[p][0], g * dx);
    atomicAdd(&s_ps[p][1], g * dy);
    atomicAdd(&s_ps[p][2], g * dz);
  }
  if (tid < 8) {
    int gp = gp0 + tid, b = gp >> 5, i = gp & 31;
    float x = rs[(b * 32 + i) * 3 + 0];
    float y = rs[(b * 32 + i) * 3 + 1];
    float z = rs[(b * 32 + i) * 3 + 2];
    float dcy = 1.0f;
#pragma unroll
    for (int n = 0; n < 8; ++n) {
      float dx = x - coords[n * 3 + 0];
      float dy = y - coords[n * 3 + 1];
      float dz = z - coords[n * 3 + 2];
      float tq = dx * dx + dy * dy + dz * dz;
      float zc = chg[n];
      dcy *= tanhf(4.0f * tq * zc * zc);
    }
    s_decay[tid] = dcy;
  }
  __syncthreads();
  if (tid < 24) {
    int p = tid / 3, c = tid - p * 3;
    int gp = gp0 + p;
    atomicAdd(&out[gp * 3 + c], OUT_SCALE * s_decay[p] * s_ps[p][c]);
  }
}

// ---------------------------------------------------------------------------
// NUC kernel: 16 pairs/block, 8 rows/pair => 128 rows, 8 tiles (no padding).
// Writes out = OUT_SCALE*decay*ps_nuc (plain store initializes out).
// ---------------------------------------------------------------------------
__global__ __launch_bounds__(256, 2) void bf_nuc_kernel(
    const float* __restrict__ rs, const float* __restrict__ msg,
    const float* __restrict__ emb, const float* __restrict__ w1,
    const float* __restrict__ b1, const float* __restrict__ w2,
    const float* __restrict__ b2, const float* __restrict__ coords,
    const float* __restrict__ chg, float* __restrict__ out) {
  __shared__ __align__(16) unsigned short s_emb[16 * 128];
  __shared__ __align__(16) unsigned short s_msg[128 * 128];
  __shared__ float s_fp[4][128];
  __shared__ float s_ps[16][4];
  __shared__ float s_decay[16];

  const int tid = threadIdx.x;
  const int bid = blockIdx.x;
  const int gp0 = bid * 16;

  if (tid < 64) ((float*)s_ps)[tid] = 0.0f;

  // ---- stage emb (16 pairs x 128) ----
  {
    int p = tid >> 4, c = tid & 15;
    const float* src = emb + (gp0 + p) * 128 + c * 8;
    float4 v0 = *(const float4*)src;
    float4 v1 = *(const float4*)(src + 4);
    uint4 pk;
    pk.x = (unsigned)f2bf(v0.x) | ((unsigned)f2bf(v0.y) << 16);
    pk.y = (unsigned)f2bf(v0.z) | ((unsigned)f2bf(v0.w) << 16);
    pk.z = (unsigned)f2bf(v1.x) | ((unsigned)f2bf(v1.y) << 16);
    pk.w = (unsigned)f2bf(v1.z) | ((unsigned)f2bf(v1.w) << 16);
    *(uint4*)(s_emb + p * 128 + c * 8) = pk;
  }

  // ---- stage msg (128 rows x 16 chunks), swizzled ----
#pragma unroll
  for (int it = 0; it < 8; ++it) {
    int id = it * 256 + tid;
    int r = id >> 4, c = id & 15;
    const float* src = msg + ((gp0 * 8) + r) * 128 + c * 8;
    float4 v0 = *(const float4*)src;
    float4 v1 = *(const float4*)(src + 4);
    uint4 pk;
    pk.x = (unsigned)f2bf(v0.x) | ((unsigned)f2bf(v0.y) << 16);
    pk.y = (unsigned)f2bf(v0.z) | ((unsigned)f2bf(v0.w) << 16);
    pk.z = (unsigned)f2bf(v1.x) | ((unsigned)f2bf(v1.y) << 16);
    pk.w = (unsigned)f2bf(v1.z) | ((unsigned)f2bf(v1.w) << 16);
    int sw = c ^ (r & 15);
    *(uint4*)(s_msg + r * 128 + sw * 8) = pk;
  }

  const int lane = tid & 63;
  const int wv = tid >> 6;
  const int cIdx = lane & 15, kg = lane >> 4;

  bf16x8 Bf[8][4];
  float b1v[4], w2v[4];
#pragma unroll
  for (int nt = 0; nt < 4; ++nt) {
    int col = wv * 64 + nt * 16 + cIdx;
    b1v[nt] = b1[col];
    w2v[nt] = w2[col];
#pragma unroll
    for (int kk = 0; kk < 8; ++kk) {
      int k0 = kk * 32 + kg * 8;
      const float* wp = w1 + k0 * 256 + col;
      bf16x8 f;
#pragma unroll
      for (int i = 0; i < 8; ++i) f[i] = (short)f2bf(wp[i * 256]);
      Bf[kk][nt] = f;
    }
  }

  __syncthreads();

#pragma unroll 1
  for (int t = 0; t < 8; ++t) {
    int r = t * 16 + cIdx;
    int p = r >> 3;  // 2 pairs per tile
    int rx = r & 15;
    const unsigned short* ep = s_emb + p * 128 + kg * 8;
    const unsigned short* mp = s_msg + r * 128;
    f32x4 acc0 = {0, 0, 0, 0}, acc1 = {0, 0, 0, 0};
    f32x4 acc2 = {0, 0, 0, 0}, acc3 = {0, 0, 0, 0};
#pragma unroll
    for (int kk = 0; kk < 8; ++kk) {
      bf16x8 a;
      if (kk < 4) {
        a = *(const bf16x8*)(ep + kk * 32);
      } else {
        int sw = (((kk - 4) * 4 + kg) ^ rx);
        a = *(const bf16x8*)(mp + sw * 8);
      }
      acc0 = __builtin_amdgcn_mfma_f32_16x16x32_bf16(a, Bf[kk][0], acc0, 0, 0, 0);
      acc1 = __builtin_amdgcn_mfma_f32_16x16x32_bf16(a, Bf[kk][1], acc1, 0, 0, 0);
      acc2 = __builtin_amdgcn_mfma_f32_16x16x32_bf16(a, Bf[kk][2], acc2, 0, 0, 0);
      acc3 = __builtin_amdgcn_mfma_f32_16x16x32_bf16(a, Bf[kk][3], acc3, 0, 0, 0);
    }
    float part[4] = {0, 0, 0, 0};
#define EPI(NT, ACC)                       \
  {                                        \
    float bb = b1v[NT], ww = w2v[NT];      \
    part[0] += silu_f(ACC[0] + bb) * ww;   \
    part[1] += silu_f(ACC[1] + bb) * ww;   \
    part[2] += silu_f(ACC[2] + bb) * ww;   \
    part[3] += silu_f(ACC[3] + bb) * ww;   \
  }
    EPI(0, acc0) EPI(1, acc1) EPI(2, acc2) EPI(3, acc3)
#undef EPI
#pragma unroll
    for (int rr = 0; rr < 4; ++rr) {
      float v = part[rr];
      v += __shfl_xor(v, 1);
      v += __shfl_xor(v, 2);
      v += __shfl_xor(v, 4);
      v += __shfl_xor(v, 8);
      if (cIdx == 0) s_fp[wv][t * 16 + kg * 4 + rr] = v;
    }
  }

  __syncthreads();

  if (tid < 128) {
    int p = tid >> 3, n = tid & 7;
    int gp = gp0 + p, b = gp >> 5, i = gp & 31;
    float dx = rs[(b * 32 + i) * 3 + 0] - coords[n * 3 + 0];
    float dy = rs[(b * 32 + i) * 3 + 1] - coords[n * 3 + 1];
    float dz = rs[(b * 32 + i) * 3 + 2] - coords[n * 3 + 2];
    float tq = dx * dx + dy * dy + dz * dz;
    float f = s_fp[0][tid] + s_fp[1][tid] + s_fp[2][tid] + s_fp[3][tid] + b2[0];
    float g = f / (1.0f + tq * sqrtf(tq));
    atomicAdd(&s_ps[p][0], g * dx);
    atomicAdd(&s_ps[p][1], g * dy);
    atomicAdd(&s_ps[p][2], g * dz);
  }
  if (tid < 16) {
    int gp = gp0 + tid, b = gp >> 5, i = gp & 31;
    float x = rs[(b * 32 + i) * 3 + 0];
    float y = rs[(b * 32 + i) * 3 + 1];
    float z = rs[(b * 32 + i) * 3 + 2];
    float dcy = 1.0f;
#pragma unroll
    for (int n = 0; n < 8; ++n) {
      float dx = x - coords[n * 3 + 0];
      float dy = y - coords[n * 3 + 1];
      float dz = z - coords[n * 3 + 2];
      float tq = dx * dx + dy * dy + dz * dz;
      float zc = chg[n];
      dcy *= tanhf(4.0f * tq * zc * zc);
    }
    s_decay[tid] = dcy;
  }
  __syncthreads();
  if (tid < 48) {
    int p = tid / 3, c = tid - p * 3;
    int gp = gp0 + p;
    out[gp * 3 + c] = OUT_SCALE * s_decay[p] * s_ps[p][c];
  }
}

extern "C" void kernel_launch(void* const* d_in, const int* in_sizes, int n_in,
                              void* d_out, int out_size, void* d_ws, size_t ws_size,
                              hipStream_t stream) {
  const float* rs       = (const float*)d_in[0];
  const float* coords   = (const float*)d_in[1];
  const float* msg_el   = (const float*)d_in[2];
  const float* msg_nuc  = (const float*)d_in[3];
  const float* emb      = (const float*)d_in[4];
  const float* w1_el    = (const float*)d_in[5];
  const float* b1_el    = (const float*)d_in[6];
  const float* w2_el    = (const float*)d_in[7];
  const float* b2_el    = (const float*)d_in[8];
  const float* w1_nuc   = (const float*)d_in[9];
  const float* b1_nuc   = (const float*)d_in[10];
  const float* w2_nuc   = (const float*)d_in[11];
  const float* b2_nuc   = (const float*)d_in[12];
  const float* chg      = (const float*)d_in[13];
  float* out = (float*)d_out;

  // NUC first: plain-stores initialize out. EL then atomicAdds its part.
  bf_nuc_kernel<<<1024, 256, 0, stream>>>(rs, msg_nuc, emb, w1_nuc, b1_nuc,
                                          w2_nuc, b2_nuc, coords, chg, out);
  bf_el_kernel<<<2048, 256, 0, stream>>>(rs, msg_el, emb, w1_el, b1_el,
                                         w2_el, b2_el, coords, chg, out);
}

// Round 3
// 194.136 us; speedup vs baseline: 1.3308x; 1.3308x over previous
//
#include <hip/hip_runtime.h>
#include <hip/hip_bf16.h>

#define OUT_SCALE 0.030197383422318501f  // exp(-3.5)

typedef __attribute__((ext_vector_type(8))) short bf16x8;
typedef __attribute__((ext_vector_type(4))) float f32x4;

__device__ __forceinline__ unsigned short f2bf(float f) {
  unsigned u = __builtin_bit_cast(unsigned, f);
  u += 0x7fffu + ((u >> 16) & 1u);
  return (unsigned short)(u >> 16);
}

__device__ __forceinline__ unsigned pk2(float a, float b) {
  return (unsigned)f2bf(a) | ((unsigned)f2bf(b) << 16);
}

__device__ __forceinline__ float silu_f(float h) {
  return h / (1.0f + __expf(-h));
}

// ---------------------------------------------------------------------------
// Prep: pack w1_el / w1_nuc into MFMA B-fragment layout, bf16.
// Fragment (mlp, kk, kg, col) = 8 bf16 of w1[kk*32+kg*8 .. +8)[col].
// Flat index: ((mlp*8 + kk)*4 + kg)*256 + col, 8 shorts each.
// ---------------------------------------------------------------------------
__global__ void prep_w1(const float* __restrict__ w1a,
                        const float* __restrict__ w1b,
                        unsigned short* __restrict__ wp) {
  int gid = blockIdx.x * 256 + threadIdx.x;  // 16384 fragments
  const float* w1 = (gid < 8192) ? w1a : w1b;
  int rem = gid & 8191;
  int kk = rem >> 10;
  int kg = (rem >> 8) & 3;
  int col = rem & 255;
  const float* src = w1 + (kk * 32 + kg * 8) * 256 + col;
  uint4 v;
  v.x = pk2(src[0 * 256], src[1 * 256]);
  v.y = pk2(src[2 * 256], src[3 * 256]);
  v.z = pk2(src[4 * 256], src[5 * 256]);
  v.w = pk2(src[6 * 256], src[7 * 256]);
  *(uint4*)(wp + (size_t)gid * 8) = v;
}

// ---------------------------------------------------------------------------
// EL kernel: 512 threads = 8 waves x 32 cols. 8 pairs/block, rows padded
// 31->32 => 256 rows, 16 M-tiles. atomicAdds into out.
// ---------------------------------------------------------------------------
__global__ __launch_bounds__(512, 4) void bf_el_kernel(
    const float* __restrict__ rs, const float* __restrict__ msg,
    const float* __restrict__ emb, const unsigned short* __restrict__ wp,
    const float* __restrict__ b1, const float* __restrict__ w2,
    const float* __restrict__ b2, const float* __restrict__ coords,
    const float* __restrict__ chg, float* __restrict__ out) {
  __shared__ __align__(16) unsigned short s_emb[8 * 128];
  __shared__ __align__(16) unsigned short s_msg[256 * 128];
  __shared__ float s_fp[8][256];
  __shared__ float s_ps[8][4];
  __shared__ float s_decay[8];

  const int tid = threadIdx.x;
  const int bid = blockIdx.x;
  const int gp0 = bid * 8;

  if (tid < 32) ((float*)s_ps)[tid] = 0.0f;

  // ---- stage emb (8 pairs x 16 chunks of 8) ----
  if (tid < 128) {
    int p = tid >> 4, c = tid & 15;
    const float* src = emb + (gp0 + p) * 128 + c * 8;
    float4 v0 = *(const float4*)src;
    float4 v1 = *(const float4*)(src + 4);
    uint4 pk;
    pk.x = pk2(v0.x, v0.y); pk.y = pk2(v0.z, v0.w);
    pk.z = pk2(v1.x, v1.y); pk.w = pk2(v1.z, v1.w);
    *(uint4*)(s_emb + p * 128 + c * 8) = pk;
  }

  // ---- stage msg (256 rows x 16 chunks), XOR-swizzled chunk index ----
#pragma unroll
  for (int it = 0; it < 8; ++it) {
    int id = it * 512 + tid;
    int r = id >> 4, c = id & 15;
    int p = r >> 5, j = r & 31;
    uint4 pk = {0u, 0u, 0u, 0u};
    if (j < 31) {
      const float* src = msg + (size_t)((gp0 + p) * 31 + j) * 128 + c * 8;
      float4 v0 = *(const float4*)src;
      float4 v1 = *(const float4*)(src + 4);
      pk.x = pk2(v0.x, v0.y); pk.y = pk2(v0.z, v0.w);
      pk.z = pk2(v1.x, v1.y); pk.w = pk2(v1.z, v1.w);
    }
    int sw = c ^ (r & 15);
    *(uint4*)(s_msg + r * 128 + sw * 8) = pk;
  }

  const int lane = tid & 63;
  const int wv = tid >> 6;          // 0..7
  const int cIdx = lane & 15, kg = lane >> 4;

  // ---- load prepacked W1 fragments (coalesced 16B loads) ----
  bf16x8 Bf[8][2];
  float b1v[2], w2v[2];
#pragma unroll
  for (int nt = 0; nt < 2; ++nt) {
    int col = wv * 32 + nt * 16 + cIdx;
    b1v[nt] = b1[col];
    w2v[nt] = w2[col];
#pragma unroll
    for (int kk = 0; kk < 8; ++kk)
      Bf[kk][nt] = *(const bf16x8*)(wp + (size_t)((kk * 4 + kg) * 256 + col) * 8);
  }

  __syncthreads();

  // ---- main loop: 16 M-tiles ----
#pragma unroll 1
  for (int t = 0; t < 16; ++t) {
    int p = t >> 1;
    int r = t * 16 + cIdx;
    int rx = r & 15;
    const unsigned short* ep = s_emb + p * 128 + kg * 8;
    const unsigned short* mp = s_msg + r * 128;
    f32x4 acc0 = {0, 0, 0, 0}, acc1 = {0, 0, 0, 0};
#pragma unroll
    for (int kk = 0; kk < 8; ++kk) {
      bf16x8 a;
      if (kk < 4) {
        a = *(const bf16x8*)(ep + kk * 32);
      } else {
        int sw = (((kk - 4) * 4 + kg) ^ rx);
        a = *(const bf16x8*)(mp + sw * 8);
      }
      acc0 = __builtin_amdgcn_mfma_f32_16x16x32_bf16(a, Bf[kk][0], acc0, 0, 0, 0);
      acc1 = __builtin_amdgcn_mfma_f32_16x16x32_bf16(a, Bf[kk][1], acc1, 0, 0, 0);
    }
    float part[4] = {0, 0, 0, 0};
#define EPI(NT, ACC)                       \
  {                                        \
    float bb = b1v[NT], ww = w2v[NT];      \
    part[0] += silu_f(ACC[0] + bb) * ww;   \
    part[1] += silu_f(ACC[1] + bb) * ww;   \
    part[2] += silu_f(ACC[2] + bb) * ww;   \
    part[3] += silu_f(ACC[3] + bb) * ww;   \
  }
    EPI(0, acc0) EPI(1, acc1)
#undef EPI
#pragma unroll
    for (int rr = 0; rr < 4; ++rr) {
      float v = part[rr];
      v += __shfl_xor(v, 1);
      v += __shfl_xor(v, 2);
      v += __shfl_xor(v, 4);
      v += __shfl_xor(v, 8);
      if (cIdx == 0) s_fp[wv][t * 16 + kg * 4 + rr] = v;
    }
  }

  __syncthreads();

  // ---- geometry epilogue ----
  if (tid < 248) {
    int p = tid / 31, jj = tid - p * 31;
    int gp = gp0 + p, b = gp >> 5, i = gp & 31;
    int jidx = jj + (jj >= i ? 1 : 0);
    const float* rsb = rs + b * 96;
    float dx = rsb[jidx * 3 + 0] - rsb[i * 3 + 0];
    float dy = rsb[jidx * 3 + 1] - rsb[i * 3 + 1];
    float dz = rsb[jidx * 3 + 2] - rsb[i * 3 + 2];
    float tq = dx * dx + dy * dy + dz * dz;
    int row = p * 32 + jj;
    float f = b2[0];
#pragma unroll
    for (int w = 0; w < 8; ++w) f += s_fp[w][row];
    float g = f / (1.0f + tq * sqrtf(tq));
    atomicAdd(&s_ps[p][0], g * dx);
    atomicAdd(&s_ps[p][1], g * dy);
    atomicAdd(&s_ps[p][2], g * dz);
  }
  if (tid < 8) {
    int gp = gp0 + tid, b = gp >> 5, i = gp & 31;
    float x = rs[(b * 32 + i) * 3 + 0];
    float y = rs[(b * 32 + i) * 3 + 1];
    float z = rs[(b * 32 + i) * 3 + 2];
    float dcy = 1.0f;
#pragma unroll
    for (int n = 0; n < 8; ++n) {
      float dx = x - coords[n * 3 + 0];
      float dy = y - coords[n * 3 + 1];
      float dz = z - coords[n * 3 + 2];
      float tq = dx * dx + dy * dy + dz * dz;
      float zc = chg[n];
      dcy *= tanhf(4.0f * tq * zc * zc);
    }
    s_decay[tid] = dcy;
  }
  __syncthreads();
  if (tid < 24) {
    int p = tid / 3, c = tid - p * 3;
    int gp = gp0 + p;
    atomicAdd(&out[gp * 3 + c], OUT_SCALE * s_decay[p] * s_ps[p][c]);
  }
}

// ---------------------------------------------------------------------------
// NUC kernel: 512 threads = 8 waves x 32 cols. 16 pairs/block, 128 rows,
// 8 M-tiles (no padding). Plain-stores out (initializes it).
// ---------------------------------------------------------------------------
__global__ __launch_bounds__(512, 4) void bf_nuc_kernel(
    const float* __restrict__ rs, const float* __restrict__ msg,
    const float* __restrict__ emb, const unsigned short* __restrict__ wp,
    const float* __restrict__ b1, const float* __restrict__ w2,
    const float* __restrict__ b2, const float* __restrict__ coords,
    const float* __restrict__ chg, float* __restrict__ out) {
  __shared__ __align__(16) unsigned short s_emb[16 * 128];
  __shared__ __align__(16) unsigned short s_msg[128 * 128];
  __shared__ float s_fp[8][128];
  __shared__ float s_ps[16][4];
  __shared__ float s_decay[16];

  const int tid = threadIdx.x;
  const int bid = blockIdx.x;
  const int gp0 = bid * 16;

  if (tid < 64) ((float*)s_ps)[tid] = 0.0f;

  // ---- stage emb (16 pairs x 16 chunks) ----
  if (tid < 256) {
    int p = tid >> 4, c = tid & 15;
    const float* src = emb + (gp0 + p) * 128 + c * 8;
    float4 v0 = *(const float4*)src;
    float4 v1 = *(const float4*)(src + 4);
    uint4 pk;
    pk.x = pk2(v0.x, v0.y); pk.y = pk2(v0.z, v0.w);
    pk.z = pk2(v1.x, v1.y); pk.w = pk2(v1.z, v1.w);
    *(uint4*)(s_emb + p * 128 + c * 8) = pk;
  }

  // ---- stage msg (128 rows x 16 chunks), swizzled ----
#pragma unroll
  for (int it = 0; it < 4; ++it) {
    int id = it * 512 + tid;
    int r = id >> 4, c = id & 15;
    const float* src = msg + (size_t)(gp0 * 8 + r) * 128 + c * 8;
    float4 v0 = *(const float4*)src;
    float4 v1 = *(const float4*)(src + 4);
    uint4 pk;
    pk.x = pk2(v0.x, v0.y); pk.y = pk2(v0.z, v0.w);
    pk.z = pk2(v1.x, v1.y); pk.w = pk2(v1.z, v1.w);
    int sw = c ^ (r & 15);
    *(uint4*)(s_msg + r * 128 + sw * 8) = pk;
  }

  const int lane = tid & 63;
  const int wv = tid >> 6;
  const int cIdx = lane & 15, kg = lane >> 4;

  bf16x8 Bf[8][2];
  float b1v[2], w2v[2];
#pragma unroll
  for (int nt = 0; nt < 2; ++nt) {
    int col = wv * 32 + nt * 16 + cIdx;
    b1v[nt] = b1[col];
    w2v[nt] = w2[col];
#pragma unroll
    for (int kk = 0; kk < 8; ++kk)
      Bf[kk][nt] = *(const bf16x8*)(wp + (size_t)((kk * 4 + kg) * 256 + col) * 8);
  }

  __syncthreads();

#pragma unroll 1
  for (int t = 0; t < 8; ++t) {
    int r = t * 16 + cIdx;
    int p = r >> 3;
    int rx = r & 15;
    const unsigned short* ep = s_emb + p * 128 + kg * 8;
    const unsigned short* mp = s_msg + r * 128;
    f32x4 acc0 = {0, 0, 0, 0}, acc1 = {0, 0, 0, 0};
#pragma unroll
    for (int kk = 0; kk < 8; ++kk) {
      bf16x8 a;
      if (kk < 4) {
        a = *(const bf16x8*)(ep + kk * 32);
      } else {
        int sw = (((kk - 4) * 4 + kg) ^ rx);
        a = *(const bf16x8*)(mp + sw * 8);
      }
      acc0 = __builtin_amdgcn_mfma_f32_16x16x32_bf16(a, Bf[kk][0], acc0, 0, 0, 0);
      acc1 = __builtin_amdgcn_mfma_f32_16x16x32_bf16(a, Bf[kk][1], acc1, 0, 0, 0);
    }
    float part[4] = {0, 0, 0, 0};
#define EPI(NT, ACC)                       \
  {                                        \
    float bb = b1v[NT], ww = w2v[NT];      \
    part[0] += silu_f(ACC[0] + bb) * ww;   \
    part[1] += silu_f(ACC[1] + bb) * ww;   \
    part[2] += silu_f(ACC[2] + bb) * ww;   \
    part[3] += silu_f(ACC[3] + bb) * ww;   \
  }
    EPI(0, acc0) EPI(1, acc1)
#undef EPI
#pragma unroll
    for (int rr = 0; rr < 4; ++rr) {
      float v = part[rr];
      v += __shfl_xor(v, 1);
      v += __shfl_xor(v, 2);
      v += __shfl_xor(v, 4);
      v += __shfl_xor(v, 8);
      if (cIdx == 0) s_fp[wv][t * 16 + kg * 4 + rr] = v;
    }
  }

  __syncthreads();

  if (tid < 128) {
    int p = tid >> 3, n = tid & 7;
    int gp = gp0 + p, b = gp >> 5, i = gp & 31;
    float dx = rs[(b * 32 + i) * 3 + 0] - coords[n * 3 + 0];
    float dy = rs[(b * 32 + i) * 3 + 1] - coords[n * 3 + 1];
    float dz = rs[(b * 32 + i) * 3 + 2] - coords[n * 3 + 2];
    float tq = dx * dx + dy * dy + dz * dz;
    float f = b2[0];
#pragma unroll
    for (int w = 0; w < 8; ++w) f += s_fp[w][tid];
    float g = f / (1.0f + tq * sqrtf(tq));
    atomicAdd(&s_ps[p][0], g * dx);
    atomicAdd(&s_ps[p][1], g * dy);
    atomicAdd(&s_ps[p][2], g * dz);
  }
  if (tid < 16) {
    int gp = gp0 + tid, b = gp >> 5, i = gp & 31;
    float x = rs[(b * 32 + i) * 3 + 0];
    float y = rs[(b * 32 + i) * 3 + 1];
    float z = rs[(b * 32 + i) * 3 + 2];
    float dcy = 1.0f;
#pragma unroll
    for (int n = 0; n < 8; ++n) {
      float dx = x - coords[n * 3 + 0];
      float dy = y - coords[n * 3 + 1];
      float dz = z - coords[n * 3 + 2];
      float tq = dx * dx + dy * dy + dz * dz;
      float zc = chg[n];
      dcy *= tanhf(4.0f * tq * zc * zc);
    }
    s_decay[tid] = dcy;
  }
  __syncthreads();
  if (tid < 48) {
    int p = tid / 3, c = tid - p * 3;
    int gp = gp0 + p;
    out[gp * 3 + c] = OUT_SCALE * s_decay[p] * s_ps[p][c];
  }
}

extern "C" void kernel_launch(void* const* d_in, const int* in_sizes, int n_in,
                              void* d_out, int out_size, void* d_ws, size_t ws_size,
                              hipStream_t stream) {
  const float* rs       = (const float*)d_in[0];
  const float* coords   = (const float*)d_in[1];
  const float* msg_el   = (const float*)d_in[2];
  const float* msg_nuc  = (const float*)d_in[3];
  const float* emb      = (const float*)d_in[4];
  const float* w1_el    = (const float*)d_in[5];
  const float* b1_el    = (const float*)d_in[6];
  const float* w2_el    = (const float*)d_in[7];
  const float* b2_el    = (const float*)d_in[8];
  const float* w1_nuc   = (const float*)d_in[9];
  const float* b1_nuc   = (const float*)d_in[10];
  const float* w2_nuc   = (const float*)d_in[11];
  const float* b2_nuc   = (const float*)d_in[12];
  const float* chg      = (const float*)d_in[13];
  float* out = (float*)d_out;

  unsigned short* wpk = (unsigned short*)d_ws;         // 256 KB used
  const unsigned short* wp_el  = wpk;                  // 8192 frags
  const unsigned short* wp_nuc = wpk + 8192 * 8;       // 8192 frags

  prep_w1<<<64, 256, 0, stream>>>(w1_el, w1_nuc, wpk);
  // NUC first: plain-stores initialize out. EL then atomicAdds its part.
  bf_nuc_kernel<<<1024, 512, 0, stream>>>(rs, msg_nuc, emb, wp_nuc, b1_nuc,
                                          w2_nuc, b2_nuc, coords, chg, out);
  bf_el_kernel<<<2048, 512, 0, stream>>>(rs, msg_el, emb, wp_el, b1_el,
                                         w2_el, b2_el, coords, chg, out);
}

// Round 4
// 170.970 us; speedup vs baseline: 1.5111x; 1.1355x over previous
//
#include <hip/hip_runtime.h>
#include <hip/hip_bf16.h>

#define OUT_SCALE 0.030197383422318501f  // exp(-3.5)

typedef __attribute__((ext_vector_type(8))) short bf16x8;
typedef __attribute__((ext_vector_type(4))) float f32x4;

#define EL_BLOCKS 2048
#define NUC_BLOCKS 1024

__device__ __forceinline__ unsigned pk2(float a, float b) {
  __hip_bfloat162 h = __float22bfloat162_rn(make_float2(a, b));
  unsigned u;
  __builtin_memcpy(&u, &h, 4);
  return u;
}

__device__ __forceinline__ float silu_f(float h) {
  // fast silu: rcp approx instead of IEEE divide (~12 ops -> ~5 ops)
  return h * __builtin_amdgcn_rcpf(1.0f + __expf(-h));
}

// ---------------------------------------------------------------------------
// Prep: pack w1_el / w1_nuc into MFMA B-fragment layout, bf16.
// Fragment (mlp, kk, kg, col) = 8 bf16 of w1[kk*32+kg*8 .. +8)[col].
// Flat index: ((mlp*8 + kk)*4 + kg)*256 + col, 8 shorts each.
// ---------------------------------------------------------------------------
__global__ void prep_w1(const float* __restrict__ w1a,
                        const float* __restrict__ w1b,
                        unsigned short* __restrict__ wp) {
  int gid = blockIdx.x * 256 + threadIdx.x;  // 16384 fragments
  const float* w1 = (gid < 8192) ? w1a : w1b;
  int rem = gid & 8191;
  int kk = rem >> 10;
  int kg = (rem >> 8) & 3;
  int col = rem & 255;
  const float* src = w1 + (kk * 32 + kg * 8) * 256 + col;
  uint4 v;
  v.x = pk2(src[0 * 256], src[1 * 256]);
  v.y = pk2(src[2 * 256], src[3 * 256]);
  v.z = pk2(src[4 * 256], src[5 * 256]);
  v.w = pk2(src[6 * 256], src[7 * 256]);
  *(uint4*)(wp + (size_t)gid * 8) = v;
}

// ---------------------------------------------------------------------------
// Fused main kernel. Blocks [0, EL_BLOCKS): el path (8 pairs, 256 rows,
// 16 M-tiles). Blocks [EL_BLOCKS, EL_BLOCKS+NUC_BLOCKS): nuc path
// (16 pairs, 128 rows, 8 M-tiles). 512 threads = 8 waves x 32 cols.
// Both paths atomicAdd into out (zeroed by hipMemsetAsync beforehand).
// ---------------------------------------------------------------------------
__global__ __launch_bounds__(512, 4) void bf_main_kernel(
    const float* __restrict__ rs, const float* __restrict__ msg_el,
    const float* __restrict__ msg_nuc, const float* __restrict__ emb,
    const unsigned short* __restrict__ wpk,
    const float* __restrict__ b1_el, const float* __restrict__ w2_el,
    const float* __restrict__ b2_el,
    const float* __restrict__ b1_nuc, const float* __restrict__ w2_nuc,
    const float* __restrict__ b2_nuc,
    const float* __restrict__ coords, const float* __restrict__ chg,
    float* __restrict__ out) {
  __shared__ __align__(16) unsigned short s_emb[16 * 128];
  __shared__ __align__(16) unsigned short s_msg[256 * 128];
  __shared__ float s_fp[8][256];
  __shared__ float s_ps[16][4];
  __shared__ float s_decay[16];

  const int tid = threadIdx.x;
  const int bid = blockIdx.x;
  const int lane = tid & 63;
  const int wv = tid >> 6;          // 0..7
  const int cIdx = lane & 15, kg = lane >> 4;

  if (bid < EL_BLOCKS) {
    // ======================= EL PATH =======================
    const int gp0 = bid * 8;
    const float* msg = msg_el;

    if (tid < 32) ((float*)s_ps)[tid] = 0.0f;

    // ---- stage emb (8 pairs x 16 chunks of 8) ----
    if (tid < 128) {
      int p = tid >> 4, c = tid & 15;
      const float* src = emb + (gp0 + p) * 128 + c * 8;
      float4 v0 = *(const float4*)src;
      float4 v1 = *(const float4*)(src + 4);
      uint4 pk;
      pk.x = pk2(v0.x, v0.y); pk.y = pk2(v0.z, v0.w);
      pk.z = pk2(v1.x, v1.y); pk.w = pk2(v1.z, v1.w);
      *(uint4*)(s_emb + p * 128 + c * 8) = pk;
    }

    // ---- stage msg (256 rows x 16 chunks), XOR-swizzled chunk index ----
#pragma unroll
    for (int it = 0; it < 8; ++it) {
      int id = it * 512 + tid;
      int r = id >> 4, c = id & 15;
      int p = r >> 5, j = r & 31;
      uint4 pk = {0u, 0u, 0u, 0u};
      if (j < 31) {
        const float* src = msg + (size_t)((gp0 + p) * 31 + j) * 128 + c * 8;
        float4 v0 = *(const float4*)src;
        float4 v1 = *(const float4*)(src + 4);
        pk.x = pk2(v0.x, v0.y); pk.y = pk2(v0.z, v0.w);
        pk.z = pk2(v1.x, v1.y); pk.w = pk2(v1.z, v1.w);
      }
      int sw = c ^ (r & 15);
      *(uint4*)(s_msg + r * 128 + sw * 8) = pk;
    }

    // ---- load prepacked W1 fragments (coalesced 16B loads) ----
    bf16x8 Bf[8][2];
    float b1v[2], w2v[2];
#pragma unroll
    for (int nt = 0; nt < 2; ++nt) {
      int col = wv * 32 + nt * 16 + cIdx;
      b1v[nt] = b1_el[col];
      w2v[nt] = w2_el[col];
#pragma unroll
      for (int kk = 0; kk < 8; ++kk)
        Bf[kk][nt] = *(const bf16x8*)(wpk + (size_t)((kk * 4 + kg) * 256 + col) * 8);
    }

    __syncthreads();

    // ---- main loop: 16 M-tiles ----
#pragma unroll 1
    for (int t = 0; t < 16; ++t) {
      int p = t >> 1;
      int r = t * 16 + cIdx;
      int rx = r & 15;
      const unsigned short* ep = s_emb + p * 128 + kg * 8;
      const unsigned short* mp = s_msg + r * 128;
      f32x4 acc0 = {0, 0, 0, 0}, acc1 = {0, 0, 0, 0};
#pragma unroll
      for (int kk = 0; kk < 8; ++kk) {
        bf16x8 a;
        if (kk < 4) {
          a = *(const bf16x8*)(ep + kk * 32);
        } else {
          int sw = (((kk - 4) * 4 + kg) ^ rx);
          a = *(const bf16x8*)(mp + sw * 8);
        }
        acc0 = __builtin_amdgcn_mfma_f32_16x16x32_bf16(a, Bf[kk][0], acc0, 0, 0, 0);
        acc1 = __builtin_amdgcn_mfma_f32_16x16x32_bf16(a, Bf[kk][1], acc1, 0, 0, 0);
      }
      float part[4] = {0, 0, 0, 0};
#define EPI(NT, ACC)                       \
  {                                        \
    float bb = b1v[NT], ww = w2v[NT];      \
    part[0] += silu_f(ACC[0] + bb) * ww;   \
    part[1] += silu_f(ACC[1] + bb) * ww;   \
    part[2] += silu_f(ACC[2] + bb) * ww;   \
    part[3] += silu_f(ACC[3] + bb) * ww;   \
  }
      EPI(0, acc0) EPI(1, acc1)
#undef EPI
#pragma unroll
      for (int rr = 0; rr < 4; ++rr) {
        float v = part[rr];
        v += __shfl_xor(v, 1);
        v += __shfl_xor(v, 2);
        v += __shfl_xor(v, 4);
        v += __shfl_xor(v, 8);
        if (cIdx == 0) s_fp[wv][t * 16 + kg * 4 + rr] = v;
      }
    }

    __syncthreads();

    // ---- geometry epilogue ----
    if (tid < 248) {
      int p = tid / 31, jj = tid - p * 31;
      int gp = gp0 + p, b = gp >> 5, i = gp & 31;
      int jidx = jj + (jj >= i ? 1 : 0);
      const float* rsb = rs + b * 96;
      float dx = rsb[jidx * 3 + 0] - rsb[i * 3 + 0];
      float dy = rsb[jidx * 3 + 1] - rsb[i * 3 + 1];
      float dz = rsb[jidx * 3 + 2] - rsb[i * 3 + 2];
      float tq = dx * dx + dy * dy + dz * dz;
      int row = p * 32 + jj;
      float f = b2_el[0];
#pragma unroll
      for (int w = 0; w < 8; ++w) f += s_fp[w][row];
      float g = f * __builtin_amdgcn_rcpf(1.0f + tq * sqrtf(tq));
      atomicAdd(&s_ps[p][0], g * dx);
      atomicAdd(&s_ps[p][1], g * dy);
      atomicAdd(&s_ps[p][2], g * dz);
    }
    if (tid < 8) {
      int gp = gp0 + tid, b = gp >> 5, i = gp & 31;
      float x = rs[(b * 32 + i) * 3 + 0];
      float y = rs[(b * 32 + i) * 3 + 1];
      float z = rs[(b * 32 + i) * 3 + 2];
      float dcy = 1.0f;
#pragma unroll
      for (int n = 0; n < 8; ++n) {
        float dx = x - coords[n * 3 + 0];
        float dy = y - coords[n * 3 + 1];
        float dz = z - coords[n * 3 + 2];
        float tq = dx * dx + dy * dy + dz * dz;
        float zc = chg[n];
        dcy *= tanhf(4.0f * tq * zc * zc);
      }
      s_decay[tid] = dcy;
    }
    __syncthreads();
    if (tid < 24) {
      int p = tid / 3, c = tid - p * 3;
      int gp = gp0 + p;
      atomicAdd(&out[gp * 3 + c], OUT_SCALE * s_decay[p] * s_ps[p][c]);
    }
  } else {
    // ======================= NUC PATH =======================
    const int nbid = bid - EL_BLOCKS;
    const int gp0 = nbid * 16;
    const float* msg = msg_nuc;
    const unsigned short* wp = wpk + 8192 * 8;

    if (tid < 64) ((float*)s_ps)[tid] = 0.0f;

    // ---- stage emb (16 pairs x 16 chunks) ----
    if (tid < 256) {
      int p = tid >> 4, c = tid & 15;
      const float* src = emb + (gp0 + p) * 128 + c * 8;
      float4 v0 = *(const float4*)src;
      float4 v1 = *(const float4*)(src + 4);
      uint4 pk;
      pk.x = pk2(v0.x, v0.y); pk.y = pk2(v0.z, v0.w);
      pk.z = pk2(v1.x, v1.y); pk.w = pk2(v1.z, v1.w);
      *(uint4*)(s_emb + p * 128 + c * 8) = pk;
    }

    // ---- stage msg (128 rows x 16 chunks), swizzled ----
#pragma unroll
    for (int it = 0; it < 4; ++it) {
      int id = it * 512 + tid;
      int r = id >> 4, c = id & 15;
      const float* src = msg + (size_t)(gp0 * 8 + r) * 128 + c * 8;
      float4 v0 = *(const float4*)src;
      float4 v1 = *(const float4*)(src + 4);
      uint4 pk;
      pk.x = pk2(v0.x, v0.y); pk.y = pk2(v0.z, v0.w);
      pk.z = pk2(v1.x, v1.y); pk.w = pk2(v1.z, v1.w);
      int sw = c ^ (r & 15);
      *(uint4*)(s_msg + r * 128 + sw * 8) = pk;
    }

    bf16x8 Bf[8][2];
    float b1v[2], w2v[2];
#pragma unroll
    for (int nt = 0; nt < 2; ++nt) {
      int col = wv * 32 + nt * 16 + cIdx;
      b1v[nt] = b1_nuc[col];
      w2v[nt] = w2_nuc[col];
#pragma unroll
      for (int kk = 0; kk < 8; ++kk)
        Bf[kk][nt] = *(const bf16x8*)(wp + (size_t)((kk * 4 + kg) * 256 + col) * 8);
    }

    __syncthreads();

#pragma unroll 1
    for (int t = 0; t < 8; ++t) {
      int r = t * 16 + cIdx;
      int p = r >> 3;
      int rx = r & 15;
      const unsigned short* ep = s_emb + p * 128 + kg * 8;
      const unsigned short* mp = s_msg + r * 128;
      f32x4 acc0 = {0, 0, 0, 0}, acc1 = {0, 0, 0, 0};
#pragma unroll
      for (int kk = 0; kk < 8; ++kk) {
        bf16x8 a;
        if (kk < 4) {
          a = *(const bf16x8*)(ep + kk * 32);
        } else {
          int sw = (((kk - 4) * 4 + kg) ^ rx);
          a = *(const bf16x8*)(mp + sw * 8);
        }
        acc0 = __builtin_amdgcn_mfma_f32_16x16x32_bf16(a, Bf[kk][0], acc0, 0, 0, 0);
        acc1 = __builtin_amdgcn_mfma_f32_16x16x32_bf16(a, Bf[kk][1], acc1, 0, 0, 0);
      }
      float part[4] = {0, 0, 0, 0};
#define EPI(NT, ACC)                       \
  {                                        \
    float bb = b1v[NT], ww = w2v[NT];      \
    part[0] += silu_f(ACC[0] + bb) * ww;   \
    part[1] += silu_f(ACC[1] + bb) * ww;   \
    part[2] += silu_f(ACC[2] + bb) * ww;   \
    part[3] += silu_f(ACC[3] + bb) * ww;   \
  }
      EPI(0, acc0) EPI(1, acc1)
#undef EPI
#pragma unroll
      for (int rr = 0; rr < 4; ++rr) {
        float v = part[rr];
        v += __shfl_xor(v, 1);
        v += __shfl_xor(v, 2);
        v += __shfl_xor(v, 4);
        v += __shfl_xor(v, 8);
        if (cIdx == 0) s_fp[wv][t * 16 + kg * 4 + rr] = v;
      }
    }

    __syncthreads();

    if (tid < 128) {
      int p = tid >> 3, n = tid & 7;
      int gp = gp0 + p, b = gp >> 5, i = gp & 31;
      float dx = rs[(b * 32 + i) * 3 + 0] - coords[n * 3 + 0];
      float dy = rs[(b * 32 + i) * 3 + 1] - coords[n * 3 + 1];
      float dz = rs[(b * 32 + i) * 3 + 2] - coords[n * 3 + 2];
      float tq = dx * dx + dy * dy + dz * dz;
      float f = b2_nuc[0];
#pragma unroll
      for (int w = 0; w < 8; ++w) f += s_fp[w][tid];
      float g = f * __builtin_amdgcn_rcpf(1.0f + tq * sqrtf(tq));
      atomicAdd(&s_ps[p][0], g * dx);
      atomicAdd(&s_ps[p][1], g * dy);
      atomicAdd(&s_ps[p][2], g * dz);
    }
    if (tid < 16) {
      int gp = gp0 + tid, b = gp >> 5, i = gp & 31;
      float x = rs[(b * 32 + i) * 3 + 0];
      float y = rs[(b * 32 + i) * 3 + 1];
      float z = rs[(b * 32 + i) * 3 + 2];
      float dcy = 1.0f;
#pragma unroll
      for (int n = 0; n < 8; ++n) {
        float dx = x - coords[n * 3 + 0];
        float dy = y - coords[n * 3 + 1];
        float dz = z - coords[n * 3 + 2];
        float tq = dx * dx + dy * dy + dz * dz;
        float zc = chg[n];
        dcy *= tanhf(4.0f * tq * zc * zc);
      }
      s_decay[tid] = dcy;
    }
    __syncthreads();
    if (tid < 48) {
      int p = tid / 3, c = tid - p * 3;
      int gp = gp0 + p;
      atomicAdd(&out[gp * 3 + c], OUT_SCALE * s_decay[p] * s_ps[p][c]);
    }
  }
}

extern "C" void kernel_launch(void* const* d_in, const int* in_sizes, int n_in,
                              void* d_out, int out_size, void* d_ws, size_t ws_size,
                              hipStream_t stream) {
  const float* rs       = (const float*)d_in[0];
  const float* coords   = (const float*)d_in[1];
  const float* msg_el   = (const float*)d_in[2];
  const float* msg_nuc  = (const float*)d_in[3];
  const float* emb      = (const float*)d_in[4];
  const float* w1_el    = (const float*)d_in[5];
  const float* b1_el    = (const float*)d_in[6];
  const float* w2_el    = (const float*)d_in[7];
  const float* b2_el    = (const float*)d_in[8];
  const float* w1_nuc   = (const float*)d_in[9];
  const float* b1_nuc   = (const float*)d_in[10];
  const float* w2_nuc   = (const float*)d_in[11];
  const float* b2_nuc   = (const float*)d_in[12];
  const float* chg      = (const float*)d_in[13];
  float* out = (float*)d_out;

  unsigned short* wpk = (unsigned short*)d_ws;  // 256 KB used

  hipMemsetAsync(out, 0, (size_t)out_size * sizeof(float), stream);
  prep_w1<<<64, 256, 0, stream>>>(w1_el, w1_nuc, wpk);
  bf_main_kernel<<<EL_BLOCKS + NUC_BLOCKS, 512, 0, stream>>>(
      rs, msg_el, msg_nuc, emb, wpk, b1_el, w2_el, b2_el, b1_nuc, w2_nuc,
      b2_nuc, coords, chg, out);
}

// Round 5
// 132.858 us; speedup vs baseline: 1.9445x; 1.2869x over previous
//
#include <hip/hip_runtime.h>
#include <hip/hip_bf16.h>

#define OUT_SCALE 0.030197383422318501f  // exp(-3.5)

typedef __attribute__((ext_vector_type(8))) short bf16x8;
typedef __attribute__((ext_vector_type(4))) float f32x4;

#define EL_BLOCKS 2048
#define NUC_BLOCKS 1024

__device__ __forceinline__ unsigned pk2(float a, float b) {
  __hip_bfloat162 h = __float22bfloat162_rn(make_float2(a, b));
  unsigned u;
  __builtin_memcpy(&u, &h, 4);
  return u;
}

__device__ __forceinline__ float silu_f(float h) {
  // fast silu: rcp approx instead of IEEE divide
  return h * __builtin_amdgcn_rcpf(1.0f + __expf(-h));
}

// ---------------------------------------------------------------------------
// Prep: pack w1_el / w1_nuc into MFMA fragment layout, bf16.
// Fragment (mlp, kk, kg, col) = 8 bf16 of w1[kk*32+kg*8 .. +8)[col].
// Used as the A operand of mfma(W1^T, msg): per-lane data is identical to
// the B-operand layout, so the same packing serves the swapped order.
// ---------------------------------------------------------------------------
__global__ void prep_w1(const float* __restrict__ w1a,
                        const float* __restrict__ w1b,
                        unsigned short* __restrict__ wp) {
  int gid = blockIdx.x * 256 + threadIdx.x;  // 16384 fragments
  const float* w1 = (gid < 8192) ? w1a : w1b;
  int rem = gid & 8191;
  int kk = rem >> 10;
  int kg = (rem >> 8) & 3;
  int col = rem & 255;
  const float* src = w1 + (kk * 32 + kg * 8) * 256 + col;
  uint4 v;
  v.x = pk2(src[0 * 256], src[1 * 256]);
  v.y = pk2(src[2 * 256], src[3 * 256]);
  v.z = pk2(src[4 * 256], src[5 * 256]);
  v.w = pk2(src[6 * 256], src[7 * 256]);
  *(uint4*)(wp + (size_t)gid * 8) = v;
}

// ---------------------------------------------------------------------------
// Fused main kernel. Blocks [0, EL_BLOCKS): el path (8 pairs, 256 rows,
// 16 M-tiles). Blocks [EL_BLOCKS, ..): nuc path (16 pairs, 128 rows, 8
// M-tiles). 512 threads = 8 waves x 32 hidden-cols.
// Swapped MFMA: D[hidden][msg-row] = W1^T x feat; lane holds 8 hidden
// activations of one msg-row -> layer-2 reduce = 8 fma + 2 shuffles.
// Both paths atomicAdd into out (zeroed by hipMemsetAsync beforehand).
// ---------------------------------------------------------------------------
__global__ __launch_bounds__(512, 4) void bf_main_kernel(
    const float* __restrict__ rs, const float* __restrict__ msg_el,
    const float* __restrict__ msg_nuc, const float* __restrict__ emb,
    const unsigned short* __restrict__ wpk,
    const float* __restrict__ b1_el, const float* __restrict__ w2_el,
    const float* __restrict__ b2_el,
    const float* __restrict__ b1_nuc, const float* __restrict__ w2_nuc,
    const float* __restrict__ b2_nuc,
    const float* __restrict__ coords, const float* __restrict__ chg,
    float* __restrict__ out) {
  __shared__ __align__(16) unsigned short s_emb[16 * 128];
  __shared__ __align__(16) unsigned short s_msg[256 * 128];
  __shared__ float s_fp[8][256];
  __shared__ float s_ps[16][4];
  __shared__ float s_decay[16];

  const int tid = threadIdx.x;
  const int bid = blockIdx.x;
  const int lane = tid & 63;
  const int wv = tid >> 6;          // 0..7
  const int cIdx = lane & 15, kg = lane >> 4;

  if (bid < EL_BLOCKS) {
    // ======================= EL PATH =======================
    const int gp0 = bid * 8;
    const float* msg = msg_el;

    if (tid < 32) ((float*)s_ps)[tid] = 0.0f;

    // ---- stage emb (8 pairs x 16 chunks of 8) ----
    if (tid < 128) {
      int p = tid >> 4, c = tid & 15;
      const float* src = emb + (gp0 + p) * 128 + c * 8;
      float4 v0 = *(const float4*)src;
      float4 v1 = *(const float4*)(src + 4);
      uint4 pk;
      pk.x = pk2(v0.x, v0.y); pk.y = pk2(v0.z, v0.w);
      pk.z = pk2(v1.x, v1.y); pk.w = pk2(v1.z, v1.w);
      *(uint4*)(s_emb + p * 128 + c * 8) = pk;
    }

    // ---- stage msg (256 rows x 16 chunks), XOR-swizzled chunk index ----
#pragma unroll
    for (int it = 0; it < 8; ++it) {
      int id = it * 512 + tid;
      int r = id >> 4, c = id & 15;
      int p = r >> 5, j = r & 31;
      uint4 pk = {0u, 0u, 0u, 0u};
      if (j < 31) {
        const float* src = msg + (size_t)((gp0 + p) * 31 + j) * 128 + c * 8;
        float4 v0 = *(const float4*)src;
        float4 v1 = *(const float4*)(src + 4);
        pk.x = pk2(v0.x, v0.y); pk.y = pk2(v0.z, v0.w);
        pk.z = pk2(v1.x, v1.y); pk.w = pk2(v1.z, v1.w);
      }
      int sw = c ^ (r & 15);
      *(uint4*)(s_msg + r * 128 + sw * 8) = pk;
    }

    // ---- load prepacked W1 fragments + per-lane b1/w2 ----
    bf16x8 Bf[8][2];
    float b1v[2][4], w2v[2][4];
#pragma unroll
    for (int nt = 0; nt < 2; ++nt) {
#pragma unroll
      for (int reg = 0; reg < 4; ++reg) {
        int h = wv * 32 + nt * 16 + kg * 4 + reg;
        b1v[nt][reg] = b1_el[h];
        w2v[nt][reg] = w2_el[h];
      }
      int col = wv * 32 + nt * 16 + cIdx;
#pragma unroll
      for (int kk = 0; kk < 8; ++kk)
        Bf[kk][nt] = *(const bf16x8*)(wpk + (size_t)((kk * 4 + kg) * 256 + col) * 8);
    }

    __syncthreads();

    // ---- main loop: 16 M-tiles ----
#pragma unroll 1
    for (int t = 0; t < 16; ++t) {
      int p = t >> 1;
      int r = t * 16 + cIdx;
      int rx = r & 15;
      const unsigned short* ep = s_emb + p * 128 + kg * 8;
      const unsigned short* mp = s_msg + r * 128;
      f32x4 acc0 = {b1v[0][0], b1v[0][1], b1v[0][2], b1v[0][3]};
      f32x4 acc1 = {b1v[1][0], b1v[1][1], b1v[1][2], b1v[1][3]};
#pragma unroll
      for (int kk = 0; kk < 8; ++kk) {
        bf16x8 a;
        if (kk < 4) {
          a = *(const bf16x8*)(ep + kk * 32);
        } else {
          int sw = (((kk - 4) * 4 + kg) ^ rx);
          a = *(const bf16x8*)(mp + sw * 8);
        }
        acc0 = __builtin_amdgcn_mfma_f32_16x16x32_bf16(Bf[kk][0], a, acc0, 0, 0, 0);
        acc1 = __builtin_amdgcn_mfma_f32_16x16x32_bf16(Bf[kk][1], a, acc1, 0, 0, 0);
      }
      float p0 = 0.0f, p1 = 0.0f;
#pragma unroll
      for (int reg = 0; reg < 4; ++reg) {
        p0 += silu_f(acc0[reg]) * w2v[0][reg];
        p1 += silu_f(acc1[reg]) * w2v[1][reg];
      }
      float v = p0 + p1;
      v += __shfl_xor(v, 16);
      v += __shfl_xor(v, 32);
      if (kg == 0) s_fp[wv][t * 16 + cIdx] = v;
    }

    __syncthreads();

    // ---- geometry epilogue ----
    if (tid < 248) {
      int p = tid / 31, jj = tid - p * 31;
      int gp = gp0 + p, b = gp >> 5, i = gp & 31;
      int jidx = jj + (jj >= i ? 1 : 0);
      const float* rsb = rs + b * 96;
      float dx = rsb[jidx * 3 + 0] - rsb[i * 3 + 0];
      float dy = rsb[jidx * 3 + 1] - rsb[i * 3 + 1];
      float dz = rsb[jidx * 3 + 2] - rsb[i * 3 + 2];
      float tq = dx * dx + dy * dy + dz * dz;
      int row = p * 32 + jj;
      float f = b2_el[0];
#pragma unroll
      for (int w = 0; w < 8; ++w) f += s_fp[w][row];
      float g = f * __builtin_amdgcn_rcpf(1.0f + tq * sqrtf(tq));
      atomicAdd(&s_ps[p][0], g * dx);
      atomicAdd(&s_ps[p][1], g * dy);
      atomicAdd(&s_ps[p][2], g * dz);
    }
    if (tid < 8) {
      int gp = gp0 + tid, b = gp >> 5, i = gp & 31;
      float x = rs[(b * 32 + i) * 3 + 0];
      float y = rs[(b * 32 + i) * 3 + 1];
      float z = rs[(b * 32 + i) * 3 + 2];
      float dcy = 1.0f;
#pragma unroll
      for (int n = 0; n < 8; ++n) {
        float dx = x - coords[n * 3 + 0];
        float dy = y - coords[n * 3 + 1];
        float dz = z - coords[n * 3 + 2];
        float tq = dx * dx + dy * dy + dz * dz;
        float zc = chg[n];
        dcy *= tanhf(4.0f * tq * zc * zc);
      }
      s_decay[tid] = dcy;
    }
    __syncthreads();
    if (tid < 24) {
      int p = tid / 3, c = tid - p * 3;
      int gp = gp0 + p;
      atomicAdd(&out[gp * 3 + c], OUT_SCALE * s_decay[p] * s_ps[p][c]);
    }
  } else {
    // ======================= NUC PATH =======================
    const int nbid = bid - EL_BLOCKS;
    const int gp0 = nbid * 16;
    const float* msg = msg_nuc;
    const unsigned short* wp = wpk + 8192 * 8;

    if (tid < 64) ((float*)s_ps)[tid] = 0.0f;

    // ---- stage emb (16 pairs x 16 chunks) ----
    if (tid < 256) {
      int p = tid >> 4, c = tid & 15;
      const float* src = emb + (gp0 + p) * 128 + c * 8;
      float4 v0 = *(const float4*)src;
      float4 v1 = *(const float4*)(src + 4);
      uint4 pk;
      pk.x = pk2(v0.x, v0.y); pk.y = pk2(v0.z, v0.w);
      pk.z = pk2(v1.x, v1.y); pk.w = pk2(v1.z, v1.w);
      *(uint4*)(s_emb + p * 128 + c * 8) = pk;
    }

    // ---- stage msg (128 rows x 16 chunks), swizzled ----
#pragma unroll
    for (int it = 0; it < 4; ++it) {
      int id = it * 512 + tid;
      int r = id >> 4, c = id & 15;
      const float* src = msg + (size_t)(gp0 * 8 + r) * 128 + c * 8;
      float4 v0 = *(const float4*)src;
      float4 v1 = *(const float4*)(src + 4);
      uint4 pk;
      pk.x = pk2(v0.x, v0.y); pk.y = pk2(v0.z, v0.w);
      pk.z = pk2(v1.x, v1.y); pk.w = pk2(v1.z, v1.w);
      int sw = c ^ (r & 15);
      *(uint4*)(s_msg + r * 128 + sw * 8) = pk;
    }

    bf16x8 Bf[8][2];
    float b1v[2][4], w2v[2][4];
#pragma unroll
    for (int nt = 0; nt < 2; ++nt) {
#pragma unroll
      for (int reg = 0; reg < 4; ++reg) {
        int h = wv * 32 + nt * 16 + kg * 4 + reg;
        b1v[nt][reg] = b1_nuc[h];
        w2v[nt][reg] = w2_nuc[h];
      }
      int col = wv * 32 + nt * 16 + cIdx;
#pragma unroll
      for (int kk = 0; kk < 8; ++kk)
        Bf[kk][nt] = *(const bf16x8*)(wp + (size_t)((kk * 4 + kg) * 256 + col) * 8);
    }

    __syncthreads();

#pragma unroll 1
    for (int t = 0; t < 8; ++t) {
      int r = t * 16 + cIdx;
      int p = r >> 3;
      int rx = r & 15;
      const unsigned short* ep = s_emb + p * 128 + kg * 8;
      const unsigned short* mp = s_msg + r * 128;
      f32x4 acc0 = {b1v[0][0], b1v[0][1], b1v[0][2], b1v[0][3]};
      f32x4 acc1 = {b1v[1][0], b1v[1][1], b1v[1][2], b1v[1][3]};
#pragma unroll
      for (int kk = 0; kk < 8; ++kk) {
        bf16x8 a;
        if (kk < 4) {
          a = *(const bf16x8*)(ep + kk * 32);
        } else {
          int sw = (((kk - 4) * 4 + kg) ^ rx);
          a = *(const bf16x8*)(mp + sw * 8);
        }
        acc0 = __builtin_amdgcn_mfma_f32_16x16x32_bf16(Bf[kk][0], a, acc0, 0, 0, 0);
        acc1 = __builtin_amdgcn_mfma_f32_16x16x32_bf16(Bf[kk][1], a, acc1, 0, 0, 0);
      }
      float p0 = 0.0f, p1 = 0.0f;
#pragma unroll
      for (int reg = 0; reg < 4; ++reg) {
        p0 += silu_f(acc0[reg]) * w2v[0][reg];
        p1 += silu_f(acc1[reg]) * w2v[1][reg];
      }
      float v = p0 + p1;
      v += __shfl_xor(v, 16);
      v += __shfl_xor(v, 32);
      if (kg == 0) s_fp[wv][t * 16 + cIdx] = v;
    }

    __syncthreads();

    if (tid < 128) {
      int p = tid >> 3, n = tid & 7;
      int gp = gp0 + p, b = gp >> 5, i = gp & 31;
      float dx = rs[(b * 32 + i) * 3 + 0] - coords[n * 3 + 0];
      float dy = rs[(b * 32 + i) * 3 + 1] - coords[n * 3 + 1];
      float dz = rs[(b * 32 + i) * 3 + 2] - coords[n * 3 + 2];
      float tq = dx * dx + dy * dy + dz * dz;
      float f = b2_nuc[0];
#pragma unroll
      for (int w = 0; w < 8; ++w) f += s_fp[w][tid];
      float g = f * __builtin_amdgcn_rcpf(1.0f + tq * sqrtf(tq));
      atomicAdd(&s_ps[p][0], g * dx);
      atomicAdd(&s_ps[p][1], g * dy);
      atomicAdd(&s_ps[p][2], g * dz);
    }
    if (tid < 16) {
      int gp = gp0 + tid, b = gp >> 5, i = gp & 31;
      float x = rs[(b * 32 + i) * 3 + 0];
      float y = rs[(b * 32 + i) * 3 + 1];
      float z = rs[(b * 32 + i) * 3 + 2];
      float dcy = 1.0f;
#pragma unroll
      for (int n = 0; n < 8; ++n) {
        float dx = x - coords[n * 3 + 0];
        float dy = y - coords[n * 3 + 1];
        float dz = z - coords[n * 3 + 2];
        float tq = dx * dx + dy * dy + dz * dz;
        float zc = chg[n];
        dcy *= tanhf(4.0f * tq * zc * zc);
      }
      s_decay[tid] = dcy;
    }
    __syncthreads();
    if (tid < 48) {
      int p = tid / 3, c = tid - p * 3;
      int gp = gp0 + p;
      atomicAdd(&out[gp * 3 + c], OUT_SCALE * s_decay[p] * s_ps[p][c]);
    }
  }
}

extern "C" void kernel_launch(void* const* d_in, const int* in_sizes, int n_in,
                              void* d_out, int out_size, void* d_ws, size_t ws_size,
                              hipStream_t stream) {
  const float* rs       = (const float*)d_in[0];
  const float* coords   = (const float*)d_in[1];
  const float* msg_el   = (const float*)d_in[2];
  const float* msg_nuc  = (const float*)d_in[3];
  const float* emb      = (const float*)d_in[4];
  const float* w1_el    = (const float*)d_in[5];
  const float* b1_el    = (const float*)d_in[6];
  const float* w2_el    = (const float*)d_in[7];
  const float* b2_el    = (const float*)d_in[8];
  const float* w1_nuc   = (const float*)d_in[9];
  const float* b1_nuc   = (const float*)d_in[10];
  const float* w2_nuc   = (const float*)d_in[11];
  const float* b2_nuc   = (const float*)d_in[12];
  const float* chg      = (const float*)d_in[13];
  float* out = (float*)d_out;

  unsigned short* wpk = (unsigned short*)d_ws;  // 256 KB used

  hipMemsetAsync(out, 0, (size_t)out_size * sizeof(float), stream);
  prep_w1<<<64, 256, 0, stream>>>(w1_el, w1_nuc, wpk);
  bf_main_kernel<<<EL_BLOCKS + NUC_BLOCKS, 512, 0, stream>>>(
      rs, msg_el, msg_nuc, emb, wpk, b1_el, w2_el, b2_el, b1_nuc, w2_nuc,
      b2_nuc, coords, chg, out);
}